// Round 2
// baseline (136.959 us; speedup 1.0000x reference)
//
#include <hip/hip_runtime.h>

// NPairCriterion on MI355X.
// batch: [B=131072, 128] f32; anchors/positives: [A=65536] i32; negatives: [A,16] i32.
// out: scalar f32 = mean_i log1p(sum_j exp(a_i·(n_ij - p_i))) + 0.005 * mean_b ||batch_b||.
// Stable LSE form: log1p(sum exp x) = m + log(exp(-m) + sum exp(x-m)), m = max(0, max x).

__device__ __forceinline__ float wave_sum(float v) {
#pragma unroll
    for (int off = 32; off > 0; off >>= 1)
        v += __shfl_xor(v, off, 64);
    return v;
}

__global__ __launch_bounds__(64) void zero_acc_kernel(double* acc) {
    if (threadIdx.x < 2) acc[threadIdx.x] = 0.0;
}

__global__ __launch_bounds__(256) void npair_kernel(
        const float* __restrict__ batch,
        const int* __restrict__ anchors,
        const int* __restrict__ positives,
        const int* __restrict__ negatives,
        double* __restrict__ acc,
        int A)
{
    const int lane = threadIdx.x & 63;
    const int wib  = threadIdx.x >> 6;          // wave index in block
    const int wpb  = blockDim.x >> 6;           // waves per block (4)
    const int nw   = gridDim.x * wpb;           // total waves
    const float2* b2 = (const float2*)batch;    // row stride = 64 float2

    float local = 0.f;
    for (int i = blockIdx.x * wpb + wib; i < A; i += nw) {
        const int ai = anchors[i];
        const int pi = positives[i];
        float2 av = b2[(size_t)ai * 64 + lane];
        float2 pv = b2[(size_t)pi * 64 + lane];
        float ap = wave_sum(av.x * pv.x + av.y * pv.y);

        // negative indices: lanes 0..15 load, broadcast via shfl
        int nidx = (lane < 16) ? negatives[(size_t)i * 16 + lane] : 0;

        float inner[16];
#pragma unroll
        for (int j = 0; j < 16; ++j) {
            int idx = __shfl(nidx, j, 64);
            float2 nv = b2[(size_t)idx * 64 + lane];
            float an = wave_sum(av.x * nv.x + av.y * nv.y);
            inner[j] = an - ap;
        }

        // stable log1p(sum exp(inner))
        float m = 0.f;
#pragma unroll
        for (int j = 0; j < 16; ++j) m = fmaxf(m, inner[j]);
        float s = expf(-m);   // the "+1" term
#pragma unroll
        for (int j = 0; j < 16; ++j) s += expf(inner[j] - m);
        local += m + logf(s); // identical across lanes

    }

    __shared__ float part[4];
    if (lane == 0) part[wib] = local;
    __syncthreads();
    if (threadIdx.x == 0) {
        float t = 0.f;
        for (int w = 0; w < wpb; ++w) t += part[w];
        atomicAdd(&acc[0], (double)t);
    }
}

__global__ __launch_bounds__(256) void l2_kernel(
        const float* __restrict__ batch, double* __restrict__ acc, int B)
{
    const int lane = threadIdx.x & 63;
    const int wib  = threadIdx.x >> 6;
    const int wpb  = blockDim.x >> 6;
    const int nw   = gridDim.x * wpb;
    const float2* b2 = (const float2*)batch;

    float local = 0.f;
    for (int r = blockIdx.x * wpb + wib; r < B; r += nw) {
        float2 v = b2[(size_t)r * 64 + lane];
        float ss = wave_sum(v.x * v.x + v.y * v.y);
        if (lane == 0) local += sqrtf(ss);
    }

    __shared__ float part[4];
    if (lane == 0) part[wib] = local;
    __syncthreads();
    if (threadIdx.x == 0) {
        float t = 0.f;
        for (int w = 0; w < wpb; ++w) t += part[w];
        atomicAdd(&acc[1], (double)t);
    }
}

__global__ __launch_bounds__(64) void finalize_kernel(
        const double* __restrict__ acc, float* __restrict__ out, int A, int B)
{
    if (threadIdx.x == 0) {
        double npair = acc[0] / (double)A;
        double l2    = 0.005 * (acc[1] / (double)B);
        out[0] = (float)(npair + l2);
    }
}

extern "C" void kernel_launch(void* const* d_in, const int* in_sizes, int n_in,
                              void* d_out, int out_size, void* d_ws, size_t ws_size,
                              hipStream_t stream) {
    const float* batch     = (const float*)d_in[0];
    const int*   anchors   = (const int*)d_in[1];
    const int*   positives = (const int*)d_in[2];
    const int*   negatives = (const int*)d_in[3];
    float*  out = (float*)d_out;
    double* acc = (double*)d_ws;

    const int A = in_sizes[1];          // 65536
    const int B = in_sizes[0] / 128;    // 131072

    hipLaunchKernelGGL(zero_acc_kernel, dim3(1), dim3(64), 0, stream, acc);
    hipLaunchKernelGGL(npair_kernel, dim3(4096), dim3(256), 0, stream,
                       batch, anchors, positives, negatives, acc, A);
    hipLaunchKernelGGL(l2_kernel, dim3(2048), dim3(256), 0, stream, batch, acc, B);
    hipLaunchKernelGGL(finalize_kernel, dim3(1), dim3(64), 0, stream, acc, out, A, B);
}